// Round 7
// baseline (275.717 us; speedup 1.0000x reference)
//
#include <hip/hip_runtime.h>
#include <hip/hip_bf16.h>

#define D_MODEL 1024
#define NH 16
#define DKH 64
#define BB 2
#define SS 2048
#define MTOT (BB * SS)  // 4096

typedef __hip_bfloat16 bf16;
typedef __attribute__((ext_vector_type(8))) short short8;
typedef __attribute__((ext_vector_type(4))) short short4v;
typedef __attribute__((ext_vector_type(4))) float floatx4;

__device__ __forceinline__ bf16 f2bf(float x) { return __float2bfloat16(x); }

// async global->LDS, 16B per lane; LDS dest must be wave-uniform (HW adds lane*16)
__device__ __forceinline__ void async_cp16(const void* g, void* l) {
  __builtin_amdgcn_global_load_lds(
      (const __attribute__((address_space(1))) unsigned int*)g,
      (__attribute__((address_space(3))) unsigned int*)l, 16, 0, 0);
}

// ---------------------------------------------------------------------------
// Weight pre-conversion: w_q|w_k|w_v|w_o fp32 -> bf16 (4 x 1M elems).
// ---------------------------------------------------------------------------
__global__ __launch_bounds__(256) void convert_w_kernel(
    const float* __restrict__ wq, const float* __restrict__ wk,
    const float* __restrict__ wv, const float* __restrict__ wo,
    bf16* __restrict__ out) {
  const int id = blockIdx.x * 256 + threadIdx.x;  // float4 index, 0..1M-1
  const int m = id >> 18;                         // matrix 0..3
  const int loc = id & 262143;
  const float* src = (m == 0) ? wq : (m == 1) ? wk : (m == 2) ? wv : wo;
  const float4 v = *(const float4*)(src + (size_t)loc * 4);
  short4v s;
  bf16* pb = (bf16*)&s;
  pb[0] = f2bf(v.x); pb[1] = f2bf(v.y); pb[2] = f2bf(v.z); pb[3] = f2bf(v.w);
  *(short4v*)(out + ((size_t)m << 20) + (size_t)loc * 4) = s;
}

// ---------------------------------------------------------------------------
// QKV GEMM: C[m][n] = sum_k A[m][k]*W[n][k] + bias[n], M=4096, N=K=1024.
// 128x128 tile, BK=32, 4 waves x (4x4) MFMA 16x16x32 bf16.
// A path: fp32 global -> VGPR (prefetched one iter ahead) -> cvt bf16 ->
//   ds_write_b64 (2-way bank pattern, free) -> 8 KB bf16 LDS buffer.
// W path: bf16 async global_load_lds (m97 pattern).
// One barrier per iter: stage(buf) | barrier | prefetch(buf^1) | compute(buf).
// LDS = 2*(8+8) = 32 KB. bm-fastest blockIdx for XCD-level A reuse.
// mode: 0 = bf16 row-major C; 1 = bf16 V^T layout [n][m].
// ---------------------------------------------------------------------------
__device__ __forceinline__ void gemm_qkv_body(const float* __restrict__ A,
                                              const bf16* __restrict__ W,
                                              const float* __restrict__ Bi,
                                              bf16* __restrict__ C, int mode) {
  constexpr int N = 1024, K = 1024;
  __shared__ bf16 As[2][128 * 32];  // 16 KB total
  __shared__ bf16 Ws[2][128 * 32];  // 16 KB total

  const int tid = threadIdx.x;
  const int w = tid >> 6, lane = tid & 63, quad = lane >> 4, n16 = lane & 15;
  const int bx = blockIdx.x;
  const int bm = bx & 31, bn = bx >> 5;  // bm-fastest
  const int wm = (w & 1) * 64, wn = (w >> 1) * 64;

  const int ra = tid >> 3, ca = tid & 7;    // A map: rows ra+{0,32,64,96}, 4-col chunk ca
  const int rb = lane >> 2, cb = lane & 3;  // W async map

  const float* Af = A + (size_t)(bm * 128) * K;
  const bf16* Wg0 = W + (size_t)(bn * 128) * K;

  float4 pa4[4];
  auto loadA = [&](int kk) {
#pragma unroll
    for (int ii = 0; ii < 4; ii++)
      pa4[ii] = *(const float4*)(Af + (size_t)(ii * 32 + ra) * K + kk + ca * 4);
  };
  auto stageA = [&](int buf) {
#pragma unroll
    for (int ii = 0; ii < 4; ii++) {
      short4v s;
      bf16* pb = (bf16*)&s;
      pb[0] = f2bf(pa4[ii].x); pb[1] = f2bf(pa4[ii].y);
      pb[2] = f2bf(pa4[ii].z); pb[3] = f2bf(pa4[ii].w);
      *(short4v*)(&As[buf][(ii * 32 + ra) * 32 + ca * 4]) = s;
    }
  };
  auto issueW = [&](int buf, int kk) {
    const bf16* Wg = Wg0 + kk;
#pragma unroll
    for (int ii = 0; ii < 2; ii++) {
      const int R = w * 32 + ii * 16 + rb;
      async_cp16(Wg + (size_t)R * K + cb * 8,
                 (void*)&Ws[buf][(w * 32 + ii * 16) * 32]);
    }
  };

  floatx4 acc[4][4] = {};
  loadA(0);
  issueW(0, 0);
  int buf = 0;
  for (int k0 = 0; k0 < K; k0 += 32) {
    stageA(buf);      // waits (vmcnt) on A regs loaded one compute-phase ago
    __syncthreads();  // drains W async (vmcnt) + A ds_writes (lgkm)
    if (k0 + 32 < K) { loadA(k0 + 32); issueW(buf ^ 1, k0 + 32); }

    short8 af[4], bfr[4];
#pragma unroll
    for (int i = 0; i < 4; i++)
      af[i] = *(const short8*)(&As[buf][(wm + i * 16 + n16) * 32 + quad * 8]);
#pragma unroll
    for (int j = 0; j < 4; j++)
      bfr[j] = *(const short8*)(&Ws[buf][(wn + j * 16 + n16) * 32 + quad * 8]);
#pragma unroll
    for (int i = 0; i < 4; i++)
#pragma unroll
      for (int j = 0; j < 4; j++)
        acc[i][j] = __builtin_amdgcn_mfma_f32_16x16x32_bf16(af[i], bfr[j], acc[i][j], 0, 0, 0);
    buf ^= 1;
  }

  float bv[4];
#pragma unroll
  for (int j = 0; j < 4; j++) bv[j] = Bi[bn * 128 + wn + j * 16 + n16];

#pragma unroll
  for (int i = 0; i < 4; i++) {
    const int rowb = bm * 128 + wm + i * 16 + quad * 4;
#pragma unroll
    for (int j = 0; j < 4; j++) {
      const int col = bn * 128 + wn + j * 16 + n16;
      if (mode == 1) {
        short4v s;
        bf16* pb = (bf16*)&s;
#pragma unroll
        for (int r = 0; r < 4; r++) pb[r] = f2bf(acc[i][j][r] + bv[j]);
        *(short4v*)(C + (size_t)col * MTOT + rowb) = s;
      } else {
#pragma unroll
        for (int r = 0; r < 4; r++)
          C[(size_t)(rowb + r) * N + col] = f2bf(acc[i][j][r] + bv[j]);
      }
    }
  }
}

__global__ __launch_bounds__(256) void gemm_qkv_kernel(
    const float* __restrict__ q_in, const float* __restrict__ k_in,
    const float* __restrict__ v_in, const bf16* __restrict__ Wb,
    const float* __restrict__ bq, const float* __restrict__ bk,
    const float* __restrict__ bv, bf16* __restrict__ Qw,
    bf16* __restrict__ Kw, bf16* __restrict__ VTw) {
  const int z = blockIdx.z;
  const float* A = (z == 0) ? q_in : (z == 1) ? k_in : v_in;
  const bf16* W = Wb + ((size_t)z << 20);
  const float* Bi = (z == 0) ? bq : (z == 1) ? bk : bv;
  bf16* C = (z == 0) ? Qw : (z == 1) ? Kw : VTw;
  gemm_qkv_body(A, W, Bi, C, (z == 2) ? 1 : 0);
}

// ---------------------------------------------------------------------------
// Out-proj GEMM: C fp32 [4096][1024] = A(bf16) @ W^T + b.  64x128 tile ->
// grid 512 = 2 blocks/CU (fixes the 1-block/CU latency exposure of the 128x128
// version). 4 waves, each 32x64 via 2x4 MFMA tiles. Fully async staging,
// double-buffered, one barrier/iter. LDS = 2*(4+8) = 24 KB.
// ---------------------------------------------------------------------------
__global__ __launch_bounds__(256) void gemm_out_kernel(
    const bf16* __restrict__ A, const bf16* __restrict__ W,
    const float* __restrict__ Bi, float* __restrict__ C) {
  constexpr int N = 1024, K = 1024;
  __shared__ bf16 As[2][64 * 32];   // 8 KB total
  __shared__ bf16 Ws[2][128 * 32];  // 16 KB total

  const int tid = threadIdx.x;
  const int w = tid >> 6, lane = tid & 63, quad = lane >> 4, n16 = lane & 15;
  const int bx = blockIdx.x;
  const int bm = bx & 63, bn = bx >> 6;  // bm-fastest
  const int wm = (w & 1) * 32, wn = (w >> 1) * 64;

  const int rl = lane >> 2, cl = lane & 3;

  const bf16* Ag0 = A + (size_t)(bm * 64) * K;
  const bf16* Wg0 = W + (size_t)(bn * 128) * K;

  auto issue = [&](int buf, int kk) {
    // A: 64 rows, one cp16 per wave (16 rows each)
    async_cp16(Ag0 + (size_t)(w * 16 + rl) * K + kk + cl * 8,
               (void*)&As[buf][(w * 16) * 32]);
    // W: 128 rows, two cp16 per wave
    const bf16* Wg = Wg0 + kk;
#pragma unroll
    for (int ii = 0; ii < 2; ii++) {
      const int R = w * 32 + ii * 16 + rl;
      async_cp16(Wg + (size_t)R * K + cl * 8,
                 (void*)&Ws[buf][(w * 32 + ii * 16) * 32]);
    }
  };

  floatx4 acc[2][4] = {};
  issue(0, 0);
  int buf = 0;
  for (int k0 = 0; k0 < K; k0 += 32) {
    __syncthreads();
    if (k0 + 32 < K) issue(buf ^ 1, k0 + 32);

    short8 af[2], bfr[4];
#pragma unroll
    for (int i = 0; i < 2; i++)
      af[i] = *(const short8*)(&As[buf][(wm + i * 16 + n16) * 32 + quad * 8]);
#pragma unroll
    for (int j = 0; j < 4; j++)
      bfr[j] = *(const short8*)(&Ws[buf][(wn + j * 16 + n16) * 32 + quad * 8]);
#pragma unroll
    for (int i = 0; i < 2; i++)
#pragma unroll
      for (int j = 0; j < 4; j++)
        acc[i][j] = __builtin_amdgcn_mfma_f32_16x16x32_bf16(af[i], bfr[j], acc[i][j], 0, 0, 0);
    buf ^= 1;
  }

  float bv[4];
#pragma unroll
  for (int j = 0; j < 4; j++) bv[j] = Bi[bn * 128 + wn + j * 16 + n16];

#pragma unroll
  for (int i = 0; i < 2; i++) {
    const int rowb = bm * 64 + wm + i * 16 + quad * 4;
#pragma unroll
    for (int j = 0; j < 4; j++) {
      const int col = bn * 128 + wn + j * 16 + n16;
#pragma unroll
      for (int r = 0; r < 4; r++)
        C[(size_t)(rowb + r) * N + col] = acc[i][j][r] + bv[j];
    }
  }
}

// ---------------------------------------------------------------------------
// Flash attention (unchanged from round 6). Grid (NH*BB, 16): x = head-batch
// (fastest -> XCD K/V L2 reuse), y = q-pair p; block handles q-tiles p and
// 31-p (uniform 17 KV-iters). 4 waves x 16 q-rows, BN=128, reg-prefetch,
// V pre-transposed. O aliases Q.
// ---------------------------------------------------------------------------
__global__ __launch_bounds__(256) void attn_kernel(const bf16* __restrict__ Q,
                                                   const bf16* __restrict__ Kg,
                                                   const bf16* __restrict__ VT,
                                                   bf16* __restrict__ O) {
  constexpr int BN = 128, LDK = 72, LDV = 136, LDP = 136;
  __shared__ bf16 Ks[128 * LDK];
  __shared__ bf16 Vs[64 * LDV];
  __shared__ bf16 Pw[4 * 16 * LDP];

  const int tid = threadIdx.x;
  const int w = tid >> 6, lane = tid & 63, quad = lane >> 4, n16 = lane & 15;
  const int hb = blockIdx.x;
  const int h = hb & 15, b = hb >> 4, p = blockIdx.y;
  const size_t qoff = (size_t)b * SS * D_MODEL + h * DKH;
  const bf16* VTh = VT + (size_t)(h * DKH) * MTOT + (size_t)b * SS;

  const int kvr = tid >> 3, ck = tid & 7;
  const int dd = tid >> 4, cv = tid & 15;

  short8 kreg[4], vreg[4];
  auto loadKV = [&](int kv0) {
#pragma unroll
    for (int ii = 0; ii < 4; ii++) {
      kreg[ii] = *(const short8*)(Kg + qoff + (size_t)(kv0 + ii * 32 + kvr) * D_MODEL + ck * 8);
      vreg[ii] = *(const short8*)(VTh + (size_t)(ii * 16 + dd) * MTOT + kv0 + cv * 8);
    }
  };

  for (int hf = 0; hf < 2; hf++) {
    const int q0 = (hf == 0) ? p * 64 : (31 - p) * 64;
    const int q0w = q0 + w * 16;
    const int nt = (q0 + 191) >> 7;

    short8 aQ0, aQ1;
    {
      const bf16* qp = Q + qoff + (size_t)(q0w + n16) * D_MODEL + quad * 8;
      aQ0 = *(const short8*)(qp);
      aQ1 = *(const short8*)(qp + 32);
    }

    floatx4 facc[4] = {};
    float m_i[4], l_i[4];
#pragma unroll
    for (int r = 0; r < 4; r++) { m_i[r] = -1e30f; l_i[r] = 0.f; }

    loadKV(0);
    for (int t = 0; t < nt; t++) {
#pragma unroll
      for (int ii = 0; ii < 4; ii++) {
        *(short8*)(&Ks[(ii * 32 + kvr) * LDK + ck * 8]) = kreg[ii];
        *(short8*)(&Vs[(ii * 16 + dd) * LDV + cv * 8]) = vreg[ii];
      }
      __syncthreads();
      if (t + 1 < nt) loadKV((t + 1) * BN);

      const int kv0 = t * BN;
      float pv[8][4];
      float mt[4] = {-1e30f, -1e30f, -1e30f, -1e30f};
      const int qrow_base = q0w + quad * 4;
#pragma unroll
      for (int blk = 0; blk < 8; blk++) {
        floatx4 z = {};
        short8 bk0 = *(const short8*)(&Ks[(blk * 16 + n16) * LDK + quad * 8]);
        short8 bk1 = *(const short8*)(&Ks[(blk * 16 + n16) * LDK + 32 + quad * 8]);
        z = __builtin_amdgcn_mfma_f32_16x16x32_bf16(aQ0, bk0, z, 0, 0, 0);
        z = __builtin_amdgcn_mfma_f32_16x16x32_bf16(aQ1, bk1, z, 0, 0, 0);
        const int kvg = kv0 + blk * 16 + n16;
#pragma unroll
        for (int r = 0; r < 4; r++) {
          float s = z[r] * 0.125f;
          if (kvg > qrow_base + r) s = -1e30f;
          pv[blk][r] = s;
          mt[r] = fmaxf(mt[r], s);
        }
      }
#pragma unroll
      for (int off = 1; off < 16; off <<= 1)
#pragma unroll
        for (int r = 0; r < 4; r++) mt[r] = fmaxf(mt[r], __shfl_xor(mt[r], off, 64));

      float alpha[4];
#pragma unroll
      for (int r = 0; r < 4; r++) {
        const float mn = fmaxf(m_i[r], mt[r]);
        alpha[r] = __expf(m_i[r] - mn);
        m_i[r] = mn;
      }
      float rs[4] = {0.f, 0.f, 0.f, 0.f};
#pragma unroll
      for (int blk = 0; blk < 8; blk++)
#pragma unroll
        for (int r = 0; r < 4; r++) {
          const float pe = __expf(pv[blk][r] - m_i[r]);
          pv[blk][r] = pe;
          rs[r] += pe;
        }
#pragma unroll
      for (int off = 1; off < 16; off <<= 1)
#pragma unroll
        for (int r = 0; r < 4; r++) rs[r] += __shfl_xor(rs[r], off, 64);
#pragma unroll
      for (int r = 0; r < 4; r++) l_i[r] = l_i[r] * alpha[r] + rs[r];
#pragma unroll
      for (int d = 0; d < 4; d++)
#pragma unroll
        for (int r = 0; r < 4; r++) facc[d][r] *= alpha[r];

      bf16* pw = &Pw[w * 16 * LDP];
#pragma unroll
      for (int blk = 0; blk < 8; blk++)
#pragma unroll
        for (int r = 0; r < 4; r++)
          pw[(quad * 4 + r) * LDP + blk * 16 + n16] = f2bf(pv[blk][r]);

      short8 aP[4];
#pragma unroll
      for (int c = 0; c < 4; c++)
        aP[c] = *(const short8*)(&pw[n16 * LDP + c * 32 + quad * 8]);

#pragma unroll
      for (int d = 0; d < 4; d++)
#pragma unroll
        for (int c = 0; c < 4; c++) {
          short8 bvf = *(const short8*)(&Vs[(d * 16 + n16) * LDV + c * 32 + quad * 8]);
          facc[d] = __builtin_amdgcn_mfma_f32_16x16x32_bf16(aP[c], bvf, facc[d], 0, 0, 0);
        }
      __syncthreads();
    }

#pragma unroll
    for (int r = 0; r < 4; r++) {
      const float inv = 1.f / l_i[r];
      const int qrow = q0w + quad * 4 + r;
      bf16* op = O + qoff + (size_t)qrow * D_MODEL;
#pragma unroll
      for (int d = 0; d < 4; d++) op[d * 16 + n16] = f2bf(facc[d][r] * inv);
    }
  }
}

// ---------------------------------------------------------------------------
extern "C" void kernel_launch(void* const* d_in, const int* in_sizes, int n_in,
                              void* d_out, int out_size, void* d_ws, size_t ws_size,
                              hipStream_t stream) {
  (void)in_sizes; (void)n_in; (void)out_size; (void)ws_size;
  const float* query  = (const float*)d_in[0];
  const float* key_in = (const float*)d_in[1];
  const float* value  = (const float*)d_in[2];
  // d_in[3] = mask (int32) — causal, applied analytically
  const float* w_q = (const float*)d_in[4];
  const float* b_q = (const float*)d_in[5];
  const float* w_k = (const float*)d_in[6];
  const float* b_k = (const float*)d_in[7];
  const float* w_v = (const float*)d_in[8];
  const float* b_v = (const float*)d_in[9];
  const float* w_o = (const float*)d_in[10];
  const float* b_o = (const float*)d_in[11];
  float* outp = (float*)d_out;

  const size_t mat = (size_t)MTOT * D_MODEL;  // 4M elems
  bf16* Qws  = (bf16*)d_ws;   // 8 MB; attention O aliases this
  bf16* Kws  = Qws + mat;     // 8 MB
  bf16* VTws = Kws + mat;     // 8 MB (V transposed, per-head rows)
  bf16* Wb   = VTws + mat;    // 8 MB: wq|wk|wv|wo bf16

  convert_w_kernel<<<4096, 256, 0, stream>>>(w_q, w_k, w_v, w_o, Wb);

  dim3 gq(256, 1, 3);  // x = bm + 32*bn (bm-fastest)
  gemm_qkv_kernel<<<gq, 256, 0, stream>>>(query, key_in, value, Wb, b_q, b_k,
                                          b_v, Qws, Kws, VTws);
  dim3 ga(NH * BB, 16);  // x = head-batch (fastest), y = q-pair
  attn_kernel<<<ga, 256, 0, stream>>>(Qws, Kws, VTws, Qws);
  gemm_out_kernel<<<512, 256, 0, stream>>>(Qws, Wb + ((size_t)3 << 20), b_o, outp);
}